// Round 2
// baseline (284.973 us; speedup 1.0000x reference)
//
#include <hip/hip_runtime.h>
#include <hip/hip_bf16.h>
#include <math.h>

// EdgeDistancesPassing: out[e] = exp(-relu(relu((f[src]-f[dst])@W1 + b1)@W2 + b2)) * f[dst]
// Linearity: (f[src]-f[dst])@W1 = P[src]-P[dst] with P = features@W1 (b1 added per-edge).
// T[node] = [P bf16 x64 | F bf16 x64] = 256 B/row (bf16-packed gather table).
// R6: edge kernel restructured per-block:
//   - 64 edges/block; indices staged in LDS via one coalesced phase (dedupes 8x idx loads,
//     removes per-wave idx->gather serial round trip)
//   - 2 edges/thread-group -> 6 gather loads in flight (2x memory-level parallelism)
//   - output staged in padded LDS, final copy phase issues fully dense 1KB/instr
//     nontemporal stores (fixes R5's half-line strided nontemporal writes)

#define D 64
#define NPB 64   // nodes per block in projection kernel
#define EPB 64   // edges per block in edge kernel

typedef float nfloat4 __attribute__((ext_vector_type(4)));      // native vec for nontemporal builtin
typedef unsigned short ushort8v __attribute__((ext_vector_type(8)));

// round-to-nearest-even fp32 -> bf16 bits (inputs are finite)
static __device__ __forceinline__ unsigned short f2bf(float f) {
    unsigned u = __float_as_uint(f);
    u += 0x7fffu + ((u >> 16) & 1u);
    return (unsigned short)(u >> 16);
}
static __device__ __forceinline__ float bf2f(unsigned short b) {
    return __uint_as_float(((unsigned)b) << 16);
}

// ---------------- Kernel 1: build T = [bf16(F@W1) | bf16(F)] ----------------
__global__ __launch_bounds__(256) void node_proj_kernel(
    const float* __restrict__ F, const float* __restrict__ W1,
    ushort4* __restrict__ T, int n_nodes)   // T: [node][32] ushort4 (256 B/row)
{
    __shared__ float4 sW4[D * 16];    // [k][col4], 16 KB
    __shared__ float4 sF4[NPB * 16];  // [node][k4], 16 KB

    const int tid = threadIdx.x;
    const int base = blockIdx.x * NPB;
    const int nrows = min(NPB, n_nodes - base);

    // Stage W1 (coalesced)
    const float4* W4 = (const float4*)W1;
#pragma unroll
    for (int i = 0; i < 4; ++i) sW4[tid + i * 256] = W4[tid + i * 256];

    // Stage feature rows (coalesced)
    const float4* Fg = (const float4*)(F + (long)base * D);
    const int totalf4 = nrows * 16;
    for (int i = tid; i < totalf4; i += 256) sF4[i] = Fg[i];
    __syncthreads();

    const int tx = tid & 15;   // col group (cols 4tx..4tx+3)
    const int ty = tid >> 4;   // node group (nodes 4ty..4ty+3)

    float4 acc[4];
#pragma unroll
    for (int i = 0; i < 4; ++i) { acc[i].x = 0.f; acc[i].y = 0.f; acc[i].z = 0.f; acc[i].w = 0.f; }

#pragma unroll
    for (int k4 = 0; k4 < 16; ++k4) {
        float4 wr[4], fr[4];
#pragma unroll
        for (int r = 0; r < 4; ++r) wr[r] = sW4[(k4 * 4 + r) * 16 + tx];
#pragma unroll
        for (int i = 0; i < 4; ++i) fr[i] = sF4[(ty * 4 + i) * 16 + k4];
#pragma unroll
        for (int i = 0; i < 4; ++i) {
            acc[i].x += fr[i].x * wr[0].x + fr[i].y * wr[1].x + fr[i].z * wr[2].x + fr[i].w * wr[3].x;
            acc[i].y += fr[i].x * wr[0].y + fr[i].y * wr[1].y + fr[i].z * wr[2].y + fr[i].w * wr[3].y;
            acc[i].z += fr[i].x * wr[0].z + fr[i].y * wr[1].z + fr[i].z * wr[2].z + fr[i].w * wr[3].z;
            acc[i].w += fr[i].x * wr[0].w + fr[i].y * wr[1].w + fr[i].z * wr[2].w + fr[i].w * wr[3].w;
        }
    }

    // Write P half (bf16): row slot tx covers cols 4tx..4tx+3
#pragma unroll
    for (int i = 0; i < 4; ++i) {
        const int n = ty * 4 + i;
        if (n < nrows) {
            ushort4 pu;
            pu.x = f2bf(acc[i].x); pu.y = f2bf(acc[i].y);
            pu.z = f2bf(acc[i].z); pu.w = f2bf(acc[i].w);
            T[(long)(base + n) * 32 + tx] = pu;
        }
    }

    // Write F half (bf16) from staged sF4: 1024 chunks / 256 threads
#pragma unroll
    for (int c = tid; c < NPB * 16; c += 256) {
        const int n = c >> 4;
        if (n < nrows) {
            const int sub = c & 15;
            const float4 f = sF4[c];
            ushort4 fu;
            fu.x = f2bf(f.x); fu.y = f2bf(f.y); fu.z = f2bf(f.z); fu.w = f2bf(f.w);
            T[(long)(base + n) * 32 + 16 + sub] = fu;
        }
    }
}

// ---------------- Kernel 2: block-batched edge epilogue ----------------
// 256 threads = 32 groups x 8 lanes; each group computes 2 edges; 64 edges/block.
__global__ __launch_bounds__(256) void edge_kernel(
    const ushort8v* __restrict__ T8,   // T viewed as rows of 16 x ushort8 (256 B/row)
    const int* __restrict__ src_idx, const int* __restrict__ dst_idx,
    const float* __restrict__ b1, const float* __restrict__ W2,
    const float* __restrict__ b2v,
    float* __restrict__ out, int n_edges)
{
    __shared__ int sIdx[2 * EPB];          // [src x64 | dst x64]
    __shared__ nfloat4 sOut[EPB * 17];     // padded rows: 16 data chunks + 1 pad (17.4 KB)

    const int tid = threadIdx.x;
    const int base = blockIdx.x * EPB;

    // Phase 1: coalesced index staging (threads 0..127)
    if (tid < 2 * EPB) {
        const int which = tid >> 6;        // 0 = src, 1 = dst
        const int t = tid & (EPB - 1);
        const int e = base + t;
        const int* p = which ? dst_idx : src_idx;
        sIdx[which * EPB + t] = (e < n_edges) ? p[e] : 0;
    }

    // Uniform per-lane MLP params (no LDS dependency; overlaps staging)
    const int lane8 = tid & 7;
    const float4 b1a = ((const float4*)b1)[lane8 * 2];
    const float4 b1b = ((const float4*)b1)[lane8 * 2 + 1];
    const float4 w2a = ((const float4*)W2)[lane8 * 2];
    const float4 w2b = ((const float4*)W2)[lane8 * 2 + 1];
    const float b2s = b2v[0];

    __syncthreads();

    // Phase 2: gathers + MLP for 2 edges per group
    const int g = tid >> 3;        // 0..31
    const int eA = 2 * g;
    const int eB = 2 * g + 1;

    const long srcA = sIdx[eA];
    const long dstA = sIdx[EPB + eA];
    const long srcB = sIdx[eB];
    const long dstB = sIdx[EPB + eB];

    // 6 independent 16B gathers in flight per lane
    const ushort8v psA = T8[srcA * 16 + lane8];
    const ushort8v pdA = T8[dstA * 16 + lane8];
    const ushort8v fdA = T8[dstA * 16 + 8 + lane8];
    const ushort8v psB = T8[srcB * 16 + lane8];
    const ushort8v pdB = T8[dstB * 16 + lane8];
    const ushort8v fdB = T8[dstB * 16 + 8 + lane8];

    const float b1r[8] = {b1a.x, b1a.y, b1a.z, b1a.w, b1b.x, b1b.y, b1b.z, b1b.w};
    const float w2r[8] = {w2a.x, w2a.y, w2a.z, w2a.w, w2b.x, w2b.y, w2b.z, w2b.w};

    float dotA = 0.f, dotB = 0.f;
#pragma unroll
    for (int j = 0; j < 8; ++j) {
        const float hA = fmaxf(bf2f(psA[j]) - bf2f(pdA[j]) + b1r[j], 0.f);
        dotA += hA * w2r[j];
        const float hB = fmaxf(bf2f(psB[j]) - bf2f(pdB[j]) + b1r[j], 0.f);
        dotB += hB * w2r[j];
    }
#pragma unroll
    for (int m = 1; m <= 4; m <<= 1) {
        dotA += __shfl_xor(dotA, m);
        dotB += __shfl_xor(dotB, m);
    }
    const float aA = __expf(-fmaxf(dotA + b2s, 0.f));
    const float aB = __expf(-fmaxf(dotB + b2s, 0.f));

    // Stage output rows in LDS (padded rows break power-of-2 conflicts)
    nfloat4 v;
    v.x = aA * bf2f(fdA[0]); v.y = aA * bf2f(fdA[1]);
    v.z = aA * bf2f(fdA[2]); v.w = aA * bf2f(fdA[3]);
    sOut[eA * 17 + 2 * lane8] = v;
    v.x = aA * bf2f(fdA[4]); v.y = aA * bf2f(fdA[5]);
    v.z = aA * bf2f(fdA[6]); v.w = aA * bf2f(fdA[7]);
    sOut[eA * 17 + 2 * lane8 + 1] = v;
    v.x = aB * bf2f(fdB[0]); v.y = aB * bf2f(fdB[1]);
    v.z = aB * bf2f(fdB[2]); v.w = aB * bf2f(fdB[3]);
    sOut[eB * 17 + 2 * lane8] = v;
    v.x = aB * bf2f(fdB[4]); v.y = aB * bf2f(fdB[5]);
    v.z = aB * bf2f(fdB[6]); v.w = aB * bf2f(fdB[7]);
    sOut[eB * 17 + 2 * lane8 + 1] = v;

    __syncthreads();

    // Phase 3: fully dense copy-out. 64 rows x 16 chunks = 1024 float4; 256 threads x 4.
    // Each store instruction writes 256 lanes-worth... per wave: 64 x 16 B = 1 KB contiguous.
    const int nE = min(EPB, n_edges - base);
#pragma unroll
    for (int i = 0; i < 4; ++i) {
        const int c = tid + i * 256;
        const int e = c >> 4;
        const int s = c & 15;
        if (e < nE) {
            const nfloat4 vv = sOut[e * 17 + s];
            __builtin_nontemporal_store(vv, (nfloat4*)(out + (((long)(base + e)) << 6) + s * 4));
        }
    }
}

extern "C" void kernel_launch(void* const* d_in, const int* in_sizes, int n_in,
                              void* d_out, int out_size, void* d_ws, size_t ws_size,
                              hipStream_t stream) {
    const float* features = (const float*)d_in[0];
    const int*   src_idx  = (const int*)d_in[1];
    const int*   dst_idx  = (const int*)d_in[2];
    const float* W1       = (const float*)d_in[3];
    const float* b1       = (const float*)d_in[4];
    const float* W2       = (const float*)d_in[5];
    const float* b2       = (const float*)d_in[6];
    float* out = (float*)d_out;

    const int n_nodes = in_sizes[0] / D;
    const int n_edges = in_sizes[1];

    ushort4* T = (ushort4*)d_ws;  // n_nodes * 256 B = 12.8 MB

    const int grid1 = (n_nodes + NPB - 1) / NPB;
    node_proj_kernel<<<grid1, 256, 0, stream>>>(features, W1, T, n_nodes);

    const int grid2 = (n_edges + EPB - 1) / EPB;
    edge_kernel<<<grid2, 256, 0, stream>>>((const ushort8v*)T, src_idx, dst_idx,
                                           b1, W2, b2, out, n_edges);
}